// Round 1
// baseline (363.079 us; speedup 1.0000x reference)
//
#include <hip/hip_runtime.h>

typedef __attribute__((ext_vector_type(8))) short short8;
typedef __attribute__((ext_vector_type(4))) float f32x4;

#define NB 8
#define NP 64
#define NS 256
#define ND 256

// round-to-nearest-even fp32 -> bf16 bits
__device__ __forceinline__ unsigned short f2bf(float f) {
    unsigned int u = __float_as_uint(f);
    u = (u + 0x7FFFu + ((u >> 16) & 1u)) >> 16;
    return (unsigned short)u;
}

// K1: per (b,p,row-block of 64): red[s] = (1/16) * sum_t w[p,s,t] * (X X^T)[s,t]
// plus per-row Sx = sum_d x, Sxx = sum_d x^2 (for BN stats), computed during staging.
__global__ __launch_bounds__(256) void k1_gemm_red(
    const float* __restrict__ x, const float* __restrict__ w,
    float* __restrict__ red, float* __restrict__ Sx, float* __restrict__ Sxx)
{
    // B tile: all 256 rows x 64-d chunk, bf16, padded stride 72 (2-way bank alias only)
    __shared__ unsigned short Bl[NS * 72];
    __shared__ float red_l[4 * 64];

    const int t    = threadIdx.x;
    const int lane = t & 63;
    const int wv   = t >> 6;          // wave 0..3 -> t-columns [64*wv, 64*wv+64)
    const int rb   = blockIdx.x & 3;  // row block
    const int p    = (blockIdx.x >> 2) & 63;
    const int b    = blockIdx.x >> 8;
    const int r0   = rb * 64;

    const float* xb = x + (size_t)(b * NP + p) * (NS * ND);

    f32x4 acc[4][4] = {};             // 64x64 per wave: 4x4 tiles of 16x16
    float sx[4]  = {0.f, 0.f, 0.f, 0.f};
    float sxx[4] = {0.f, 0.f, 0.f, 0.f};

    const int row16 = t >> 4;         // 0..15
    const int c4    = t & 15;         // float4 column within 64-wide chunk

    for (int d0 = 0; d0 < ND; d0 += 64) {
        __syncthreads();
        // stage all 256 rows of this d-chunk, fp32 -> bf16
        for (int i = 0; i < 16; ++i) {
            int row = row16 + 16 * i;
            f32x4 v = *reinterpret_cast<const f32x4*>(xb + row * ND + d0 + 4 * c4);
            if ((i >> 2) == rb) {     // this wg owns stats for rows [r0, r0+64)
                int slot = i & 3;
                sx[slot]  += v.x + v.y + v.z + v.w;
                sxx[slot] += v.x * v.x + v.y * v.y + v.z * v.z + v.w * v.w;
            }
            unsigned long long pk =
                  (unsigned long long)f2bf(v.x)
                | ((unsigned long long)f2bf(v.y) << 16)
                | ((unsigned long long)f2bf(v.z) << 32)
                | ((unsigned long long)f2bf(v.w) << 48);
            *reinterpret_cast<unsigned long long*>(&Bl[row * 72 + 4 * c4]) = pk;
        }
        __syncthreads();
        #pragma unroll
        for (int k0 = 0; k0 < 64; k0 += 32) {
            const int kof = k0 + (lane >> 4) * 8;
            short8 afr[4], bfr[4];
            #pragma unroll
            for (int i = 0; i < 4; ++i)
                afr[i] = *reinterpret_cast<const short8*>(
                    &Bl[(r0 + 16 * i + (lane & 15)) * 72 + kof]);
            #pragma unroll
            for (int j = 0; j < 4; ++j)
                bfr[j] = *reinterpret_cast<const short8*>(
                    &Bl[(64 * wv + 16 * j + (lane & 15)) * 72 + kof]);
            #pragma unroll
            for (int i = 0; i < 4; ++i)
                #pragma unroll
                for (int j = 0; j < 4; ++j)
                    acc[i][j] = __builtin_amdgcn_mfma_f32_16x16x32_bf16(
                        afr[i], bfr[j], acc[i][j], 0, 0, 0);
        }
    }

    const size_t rowbase = (size_t)(b * NP + p) * NS;

    // ---- per-row Sx / Sxx: reduce across the 16 lanes sharing a row ----
    #pragma unroll
    for (int slot = 0; slot < 4; ++slot) {
        float a = sx[slot], q = sxx[slot];
        #pragma unroll
        for (int off = 1; off < 16; off <<= 1) {
            a += __shfl_xor(a, off, 64);
            q += __shfl_xor(q, off, 64);
        }
        if ((lane & 15) == 0) {
            int row = r0 + 16 * slot + row16;
            Sx[rowbase + row]  = a;
            Sxx[rowbase + row] = q;
        }
    }

    // ---- weighted reduction over t: C layout col=lane&15, row=(lane>>4)*4+reg ----
    const int qd = lane >> 4;
    const int c  = lane & 15;
    const float* wp = w + (size_t)p * (NS * NS) + (size_t)r0 * NS;
    #pragma unroll
    for (int i = 0; i < 4; ++i) {
        #pragma unroll
        for (int r = 0; r < 4; ++r) {
            int row = 16 * i + 4 * qd + r;   // local row within [0,64)
            const float* wrow = wp + row * NS + 64 * wv + c;
            float s = acc[i][0][r] * wrow[0]
                    + acc[i][1][r] * wrow[16]
                    + acc[i][2][r] * wrow[32]
                    + acc[i][3][r] * wrow[48];
            #pragma unroll
            for (int off = 1; off < 16; off <<= 1)
                s += __shfl_xor(s, off, 64);
            if (c == 0) red_l[wv * 64 + row] = s;
        }
    }
    __syncthreads();
    if (t < 64) {
        float v = red_l[t] + red_l[64 + t] + red_l[128 + t] + red_l[192 + t];
        red[rowbase + r0 + t] = v * 0.0625f;   // * 1/sqrt(D)
    }
}

// K2: per-channel BN stats -> scale/bias
__global__ __launch_bounds__(256) void k2_stats(
    const float* __restrict__ red, const float* __restrict__ Sx,
    const float* __restrict__ Sxx, const float* __restrict__ gamma,
    const float* __restrict__ beta, float* __restrict__ sb)
{
    __shared__ float l1[256], l2[256];
    const int p = blockIdx.x;
    const int t = threadIdx.x;
    float sy = 0.f, syy = 0.f;
    for (int n = t; n < NB * NS; n += 256) {
        int bb = n >> 8, s = n & 255;
        size_t idx = (size_t)(bb * NP + p) * NS + s;
        float r = red[idx], a = Sx[idx], q = Sxx[idx];
        sy  += a + 256.f * r;
        syy += q + 2.f * r * a + 256.f * r * r;
    }
    l1[t] = sy; l2[t] = syy;
    __syncthreads();
    for (int off = 128; off > 0; off >>= 1) {
        if (t < off) { l1[t] += l1[t + off]; l2[t] += l2[t + off]; }
        __syncthreads();
    }
    if (t == 0) {
        const float invN = 1.f / (float)(NB * NS * ND);
        float mean = l1[0] * invN;
        float var  = l2[0] * invN - mean * mean;
        float sc   = gamma[p] * rsqrtf(var + 1e-5f);
        sb[p]      = sc;
        sb[64 + p] = beta[p] - mean * sc;
    }
}

// K3: out = (x + red) * scale[p] + bias[p], streaming float4
__global__ __launch_bounds__(256) void k3_norm(
    const float* __restrict__ x, const float* __restrict__ red,
    const float* __restrict__ sb, float* __restrict__ out)
{
    const size_t f = (size_t)blockIdx.x * 256 + threadIdx.x; // float4 index
    f32x4 v = reinterpret_cast<const f32x4*>(x)[f];
    const float r  = red[f >> 6];          // row index = elem>>8 = f>>6
    const int   p  = (int)((f >> 14) & 63);
    const float sc = sb[p];
    const float bi = sb[64 + p];
    v = (v + r) * sc + bi;
    reinterpret_cast<f32x4*>(out)[f] = v;
}

extern "C" void kernel_launch(void* const* d_in, const int* in_sizes, int n_in,
                              void* d_out, int out_size, void* d_ws, size_t ws_size,
                              hipStream_t stream)
{
    const float* x     = (const float*)d_in[0];
    const float* w     = (const float*)d_in[1];
    const float* gamma = (const float*)d_in[2];
    const float* beta  = (const float*)d_in[3];
    float* out = (float*)d_out;

    float* red = (float*)d_ws;                  // NB*NP*NS floats
    float* Sx  = red + (size_t)NB * NP * NS;
    float* Sxx = Sx  + (size_t)NB * NP * NS;
    float* sb  = Sxx + (size_t)NB * NP * NS;    // 128 floats (scale, bias)

    hipLaunchKernelGGL(k1_gemm_red, dim3(NB * NP * 4), dim3(256), 0, stream,
                       x, w, red, Sx, Sxx);
    hipLaunchKernelGGL(k2_stats, dim3(NP), dim3(256), 0, stream,
                       red, Sx, Sxx, gamma, beta, sb);
    hipLaunchKernelGGL(k3_norm, dim3((NB * NP * NS * ND) / (4 * 256)), dim3(256),
                       0, stream, x, red, sb, out);
}